// Round 10
// baseline (205.298 us; speedup 1.0000x reference)
//
#include <hip/hip_runtime.h>
#include <hip/hip_bf16.h>

typedef __attribute__((ext_vector_type(8))) short bf16x8;
typedef __attribute__((ext_vector_type(4))) float f32x4;

static __device__ __forceinline__ float bflo(unsigned int w) {
    union { unsigned int i; float f; } u; u.i = w << 16; return u.f;
}
static __device__ __forceinline__ float bfhi(unsigned int w) {
    union { unsigned int i; float f; } u; u.i = w & 0xffff0000u; return u.f;
}
static __device__ __forceinline__ unsigned short f2bf(float f) {
    __hip_bfloat16 h = __float2bfloat16(f);
    union { __hip_bfloat16 b; unsigned short s; } u; u.b = h; return u.s;
}

// ---------------------------------------------------------------------------
// degree histogram via per-block LDS histogram (kills atomic contention).
// 256 blocks x 2048-edge chunks; flush nonzero bins coalesced.
// ---------------------------------------------------------------------------
__global__ __launch_bounds__(256) void count_lds_kernel(const int* __restrict__ dst,
                                                        int* __restrict__ counts, int E) {
    __shared__ int hist[16384];
    for (int i = threadIdx.x; i < 16384; i += 256) hist[i] = 0;
    __syncthreads();
    int chunk = (E + gridDim.x - 1) / gridDim.x;
    int b0 = blockIdx.x * chunk;
    int b1 = min(E, b0 + chunk);
    for (int e = b0 + threadIdx.x; e < b1; e += 256)
        atomicAdd(&hist[dst[e]], 1);
    __syncthreads();
    for (int i = threadIdx.x; i < 16384; i += 256) {
        int c = hist[i];
        if (c) atomicAdd(&counts[i], c);
    }
}

// ---------------------------------------------------------------------------
// single-block scan, coalesced column-major bucket order.
// Consumers use row_ptr[v] + counts[v] as bucket end (order-free).
// ---------------------------------------------------------------------------
__global__ __launch_bounds__(256) void scan_kernel(const int* __restrict__ counts,
                                                   int* __restrict__ row_ptr,
                                                   float* __restrict__ dinv, int n) {
    int t = threadIdx.x;
    int rows = n >> 8;
    int s = 0;
    for (int i = 0; i < rows; ++i) s += counts[i * 256 + t];
    __shared__ int sums[256];
    sums[t] = s;
    __syncthreads();
#pragma unroll
    for (int off = 1; off < 256; off <<= 1) {
        int v = (t >= off) ? sums[t - off] : 0;
        __syncthreads();
        sums[t] += v;
        __syncthreads();
    }
    int run = (t > 0) ? sums[t - 1] : 0;
    for (int i = 0; i < rows; ++i) {
        int v = i * 256 + t;
        int c = counts[v];
        row_ptr[v] = run;
        dinv[v] = rsqrtf((float)(c + 1));
        run += c;
    }
}

// ---------------------------------------------------------------------------
// scatter via per-block LDS two-pass: local histogram -> block reservation
// (one coalesced global atomic per nonzero bin) -> replay with LDS position
// counters. No per-edge global atomics. Packed {src, dinv[src]} records.
// ---------------------------------------------------------------------------
__global__ __launch_bounds__(256) void scatter_lds_kernel(
    const int* __restrict__ src, const int* __restrict__ dst,
    const int* __restrict__ row_ptr, int* __restrict__ wp,
    const float* __restrict__ dinv, int2* __restrict__ edges, int E) {
    __shared__ int harr[16384];
    for (int i = threadIdx.x; i < 16384; i += 256) harr[i] = 0;
    __syncthreads();
    int chunk = (E + gridDim.x - 1) / gridDim.x;
    int b0 = blockIdx.x * chunk;
    int b1 = min(E, b0 + chunk);
    for (int e = b0 + threadIdx.x; e < b1; e += 256)
        atomicAdd(&harr[dst[e]], 1);
    __syncthreads();
    for (int i = threadIdx.x; i < 16384; i += 256) {
        int c = harr[i];
        harr[i] = c ? atomicAdd(&wp[i], c) : 0;   // old value = this block's base
    }
    __syncthreads();
    for (int e = b0 + threadIdx.x; e < b1; e += 256) {
        int d = dst[e];
        int s = src[e];
        int p = atomicAdd(&harr[d], 1);           // LDS: base, base+1, ...
        int2 pk;
        pk.x = s;
        pk.y = __float_as_int(dinv[s]);
        edges[row_ptr[d] + p] = pk;
    }
}

// ---------------------------------------------------------------------------
// merged prep: h0 (bf16) + transposed bf16 weights + zero counts/wp.
// ---------------------------------------------------------------------------
__global__ void prep_kernel(const int* __restrict__ x, const float* __restrict__ emb,
                            const float* __restrict__ W1, const float* __restrict__ W2,
                            const float* __restrict__ Wl,
                            unsigned short* __restrict__ h0,
                            unsigned short* __restrict__ W1t,
                            unsigned short* __restrict__ W2t,
                            unsigned short* __restrict__ Wlt,
                            int* __restrict__ counts, int* __restrict__ wp,
                            int nu, int n) {
    int i = blockIdx.x * blockDim.x + threadIdx.x;
    int H = n * 16;
    if (i < H) {
        int node = i >> 4, c8 = i & 15;
        int row = (node < nu) ? 0 : (x[node] - nu + 1);
        float4 f0 = reinterpret_cast<const float4*>(emb)[(size_t)row * 32 + c8 * 2];
        float4 f1 = reinterpret_cast<const float4*>(emb)[(size_t)row * 32 + c8 * 2 + 1];
        union { unsigned short s[8]; uint4 v; } o;
        o.s[0] = f2bf(f0.x); o.s[1] = f2bf(f0.y); o.s[2] = f2bf(f0.z); o.s[3] = f2bf(f0.w);
        o.s[4] = f2bf(f1.x); o.s[5] = f2bf(f1.y); o.s[6] = f2bf(f1.z); o.s[7] = f2bf(f1.w);
        *reinterpret_cast<uint4*>(h0 + (size_t)node * 128 + c8 * 8) = o.v;
        return;
    }
    int j = i - H;
    if (j < 32768) {
        int nn = j >> 7, kk = j & 127;
        W1t[j] = f2bf(W1[kk * 256 + nn]);
        return;
    }
    if (j < 65536) {
        int jj = j - 32768;
        int nn = jj >> 8, kk = jj & 255;
        W2t[jj] = f2bf(W2[kk * 128 + nn]);
        return;
    }
    if (j < 73728) {
        int jj = j - 65536;
        int nn = jj >> 7, kk = jj & 127;
        Wlt[jj] = f2bf(Wl[kk * 64 + nn]);
        return;
    }
    int z = j - 73728;
    if (z < n) { counts[z] = 0; return; }
    z -= n;
    if (z < n) { wp[z] = 0; }
}

// ---------------------------------------------------------------------------
// one-wave aggregation of node v -> LDS row (bf16).
// ---------------------------------------------------------------------------
static __device__ __forceinline__ void agg_node_to_lds(
    const unsigned short* __restrict__ in, unsigned short* lds_row,
    int v, int lane, const int* __restrict__ row_ptr, const int* __restrict__ cnt,
    const int2* __restrict__ edges, const float* __restrict__ dinv,
    const float* __restrict__ bias, int relu) {
    int l16 = lane & 15;
    int g = lane >> 4;
    float acc[8] = {0.f, 0.f, 0.f, 0.f, 0.f, 0.f, 0.f, 0.f};
    int s0 = row_ptr[v];
    int s1 = s0 + cnt[v];
    int e = s0 + g;
    for (; e + 4 < s1; e += 8) {
        int2 pa = edges[e];
        int2 pb = edges[e + 4];
        float wa = __int_as_float(pa.y);
        float wb = __int_as_float(pb.y);
        uint4 ra = *reinterpret_cast<const uint4*>(in + (size_t)pa.x * 128 + l16 * 8);
        uint4 rb = *reinterpret_cast<const uint4*>(in + (size_t)pb.x * 128 + l16 * 8);
        acc[0] = fmaf(wa, bflo(ra.x), acc[0]);
        acc[1] = fmaf(wa, bfhi(ra.x), acc[1]);
        acc[2] = fmaf(wa, bflo(ra.y), acc[2]);
        acc[3] = fmaf(wa, bfhi(ra.y), acc[3]);
        acc[4] = fmaf(wa, bflo(ra.z), acc[4]);
        acc[5] = fmaf(wa, bfhi(ra.z), acc[5]);
        acc[6] = fmaf(wa, bflo(ra.w), acc[6]);
        acc[7] = fmaf(wa, bfhi(ra.w), acc[7]);
        acc[0] = fmaf(wb, bflo(rb.x), acc[0]);
        acc[1] = fmaf(wb, bfhi(rb.x), acc[1]);
        acc[2] = fmaf(wb, bflo(rb.y), acc[2]);
        acc[3] = fmaf(wb, bfhi(rb.y), acc[3]);
        acc[4] = fmaf(wb, bflo(rb.z), acc[4]);
        acc[5] = fmaf(wb, bfhi(rb.z), acc[5]);
        acc[6] = fmaf(wb, bflo(rb.w), acc[6]);
        acc[7] = fmaf(wb, bfhi(rb.w), acc[7]);
    }
    if (e < s1) {
        int2 pa = edges[e];
        float wa = __int_as_float(pa.y);
        uint4 ra = *reinterpret_cast<const uint4*>(in + (size_t)pa.x * 128 + l16 * 8);
        acc[0] = fmaf(wa, bflo(ra.x), acc[0]);
        acc[1] = fmaf(wa, bfhi(ra.x), acc[1]);
        acc[2] = fmaf(wa, bflo(ra.y), acc[2]);
        acc[3] = fmaf(wa, bfhi(ra.y), acc[3]);
        acc[4] = fmaf(wa, bflo(ra.z), acc[4]);
        acc[5] = fmaf(wa, bfhi(ra.z), acc[5]);
        acc[6] = fmaf(wa, bflo(ra.w), acc[6]);
        acc[7] = fmaf(wa, bfhi(ra.w), acc[7]);
    }
#pragma unroll
    for (int d = 0; d < 8; ++d) {
        acc[d] += __shfl_xor(acc[d], 16, 64);
        acc[d] += __shfl_xor(acc[d], 32, 64);
    }
    if (g == 0) {
        float dv = dinv[v];
        uint4 sp = *reinterpret_cast<const uint4*>(in + (size_t)v * 128 + l16 * 8);
        float self[8] = {bflo(sp.x), bfhi(sp.x), bflo(sp.y), bfhi(sp.y),
                         bflo(sp.z), bfhi(sp.z), bflo(sp.w), bfhi(sp.w)};
        union { unsigned short s[8]; uint4 u; } o;
#pragma unroll
        for (int d = 0; d < 8; ++d) {
            float val = (acc[d] + dv * self[d]) * dv;
            if (bias) val += bias[l16 * 8 + d];
            if (relu) val = fmaxf(val, 0.f);
            o.s[d] = f2bf(val);
        }
        *reinterpret_cast<uint4*>(lds_row + l16 * 8) = o.u;
    }
}

// ---------------------------------------------------------------------------
// fused conv1: block = 16 nodes. agg -> gemm1(relu) -> gemm2 -> hw2
// ---------------------------------------------------------------------------
__global__ __launch_bounds__(256) void fused_conv1_kernel(
    const unsigned short* __restrict__ h0b, unsigned short* __restrict__ hw2b,
    const int* __restrict__ row_ptr, const int* __restrict__ cnt,
    const int2* __restrict__ edges, const float* __restrict__ dinv,
    const unsigned short* __restrict__ W1t, const float* __restrict__ b1,
    const unsigned short* __restrict__ W2t) {
    __shared__ unsigned short zt[16][136];
    __shared__ unsigned short h1t[16][264];
    int wid = threadIdx.x >> 6, lane = threadIdx.x & 63;
    int base = blockIdx.x * 16;
#pragma unroll
    for (int q = 0; q < 4; ++q) {
        int loc = wid * 4 + q;
        agg_node_to_lds(h0b, &zt[loc][0], base + loc, lane, row_ptr, cnt, edges, dinv,
                        nullptr, 0);
    }
    __syncthreads();
    int lr = lane & 15, kg = (lane >> 4) * 8;
    int rq = (lane >> 4) * 4;
    {
        int bn = wid * 64;
        f32x4 acc[4] = {{0,0,0,0},{0,0,0,0},{0,0,0,0},{0,0,0,0}};
        for (int k0 = 0; k0 < 128; k0 += 32) {
            bf16x8 a = *reinterpret_cast<const bf16x8*>(&zt[lr][k0 + kg]);
#pragma unroll
            for (int c = 0; c < 4; ++c) {
                bf16x8 b = *reinterpret_cast<const bf16x8*>(W1t + (size_t)(bn + c * 16 + lr) * 128 + k0 + kg);
                acc[c] = __builtin_amdgcn_mfma_f32_16x16x32_bf16(a, b, acc[c], 0, 0, 0);
            }
        }
#pragma unroll
        for (int c = 0; c < 4; ++c) {
            int col = bn + c * 16 + lr;
            float bs = b1[col];
#pragma unroll
            for (int q = 0; q < 4; ++q) {
                float vv = fmaxf(acc[c][q] + bs, 0.f);
                h1t[rq + q][col] = f2bf(vv);
            }
        }
    }
    __syncthreads();
    {
        int bn = wid * 32;
        f32x4 acc[2] = {{0,0,0,0},{0,0,0,0}};
        for (int k0 = 0; k0 < 256; k0 += 32) {
            bf16x8 a = *reinterpret_cast<const bf16x8*>(&h1t[lr][k0 + kg]);
#pragma unroll
            for (int c = 0; c < 2; ++c) {
                bf16x8 b = *reinterpret_cast<const bf16x8*>(W2t + (size_t)(bn + c * 16 + lr) * 256 + k0 + kg);
                acc[c] = __builtin_amdgcn_mfma_f32_16x16x32_bf16(a, b, acc[c], 0, 0, 0);
            }
        }
#pragma unroll
        for (int c = 0; c < 2; ++c) {
            int col = bn + c * 16 + lr;
#pragma unroll
            for (int q = 0; q < 4; ++q)
                hw2b[(size_t)(base + rq + q) * 128 + col] = f2bf(acc[c][q]);
        }
    }
}

// ---------------------------------------------------------------------------
// fused conv2: block = 16 nodes. agg(+b2,relu) -> gemm3(+bl,relu) -> h3
// ---------------------------------------------------------------------------
__global__ __launch_bounds__(256) void fused_conv2_kernel(
    const unsigned short* __restrict__ hw2b, unsigned short* __restrict__ h3b,
    const int* __restrict__ row_ptr, const int* __restrict__ cnt,
    const int2* __restrict__ edges, const float* __restrict__ dinv,
    const float* __restrict__ b2,
    const unsigned short* __restrict__ Wlt, const float* __restrict__ bl) {
    __shared__ unsigned short ht[16][136];
    int wid = threadIdx.x >> 6, lane = threadIdx.x & 63;
    int base = blockIdx.x * 16;
#pragma unroll
    for (int q = 0; q < 4; ++q) {
        int loc = wid * 4 + q;
        agg_node_to_lds(hw2b, &ht[loc][0], base + loc, lane, row_ptr, cnt, edges, dinv,
                        b2, 1);
    }
    __syncthreads();
    int lr = lane & 15, kg = (lane >> 4) * 8;
    int rq = (lane >> 4) * 4;
    f32x4 acc = {0, 0, 0, 0};
    for (int k0 = 0; k0 < 128; k0 += 32) {
        bf16x8 a = *reinterpret_cast<const bf16x8*>(&ht[lr][k0 + kg]);
        bf16x8 b = *reinterpret_cast<const bf16x8*>(Wlt + (size_t)(wid * 16 + lr) * 128 + k0 + kg);
        acc = __builtin_amdgcn_mfma_f32_16x16x32_bf16(a, b, acc, 0, 0, 0);
    }
    int col = wid * 16 + lr;
    float bs = bl[col];
#pragma unroll
    for (int q = 0; q < 4; ++q) {
        float vv = fmaxf(acc[q] + bs, 0.f);
        h3b[(size_t)(base + rq + q) * 64 + col] = f2bf(vv);
    }
}

// ---------------------------------------------------------------------------
// final: out[i][j] = clip(dot64(users[i], items[j]), 1, 5)  via bf16 MFMA.
// ---------------------------------------------------------------------------
__global__ __launch_bounds__(256) void final_gemm_kernel(
    const short* __restrict__ h3b, float* __restrict__ out, int nu, int ni) {
    __shared__ float tile[4][16][65];
    int wid = threadIdx.x >> 6, lane = threadIdx.x & 63;
    int row0 = blockIdx.x * 128 + (wid >> 1) * 64;
    int col0 = blockIdx.y * 128 + (wid & 1) * 64;
    int lr = lane & 15;
    int kg = (lane >> 4) * 8;
    const short* Au = h3b;
    const short* Bi = h3b + (size_t)nu * 64;
    bf16x8 a[4][2], b[4][2];
#pragma unroll
    for (int r = 0; r < 4; ++r)
#pragma unroll
        for (int kt = 0; kt < 2; ++kt) {
            a[r][kt] = *reinterpret_cast<const bf16x8*>(Au + (size_t)(row0 + r * 16 + lr) * 64 + kt * 32 + kg);
            b[r][kt] = *reinterpret_cast<const bf16x8*>(Bi + (size_t)(col0 + r * 16 + lr) * 64 + kt * 32 + kg);
        }
    f32x4 acc[4][4];
#pragma unroll
    for (int r = 0; r < 4; ++r)
#pragma unroll
        for (int c = 0; c < 4; ++c) {
            f32x4 z = {0.f, 0.f, 0.f, 0.f};
            z = __builtin_amdgcn_mfma_f32_16x16x32_bf16(a[r][0], b[c][0], z, 0, 0, 0);
            z = __builtin_amdgcn_mfma_f32_16x16x32_bf16(a[r][1], b[c][1], z, 0, 0, 0);
            acc[r][c] = z;
        }
    int rq = (lane >> 4) * 4;
    int orow = lane >> 4;
#pragma unroll
    for (int r = 0; r < 4; ++r) {
        __syncthreads();
#pragma unroll
        for (int c = 0; c < 4; ++c)
#pragma unroll
            for (int q = 0; q < 4; ++q) {
                float v = acc[r][c][q];
                v = fminf(fmaxf(v, 1.f), 5.f);
                tile[wid][rq + q][c * 16 + lr] = v;
            }
        __syncthreads();
#pragma unroll
        for (int rr = 0; rr < 4; ++rr) {
            float4 vv = *reinterpret_cast<const float4*>(&tile[wid][rr * 4 + orow][lr * 4]);
            *reinterpret_cast<float4*>(
                &out[(size_t)(row0 + r * 16 + rr * 4 + orow) * ni + col0 + lr * 4]) = vv;
        }
    }
}

// ---------------------------------------------------------------------------
extern "C" void kernel_launch(void* const* d_in, const int* in_sizes, int n_in,
                              void* d_out, int out_size, void* d_ws, size_t ws_size,
                              hipStream_t stream) {
    const int*   x   = (const int*)d_in[0];
    const int*   ei  = (const int*)d_in[1];
    const float* emb = (const float*)d_in[3];
    const float* W1  = (const float*)d_in[4];
    const float* b1  = (const float*)d_in[5];
    const float* W2  = (const float*)d_in[6];
    const float* b2  = (const float*)d_in[7];
    const float* Wl  = (const float*)d_in[8];
    const float* bl  = (const float*)d_in[9];
    float* out = (float*)d_out;

    const int n   = in_sizes[0];                 // 16384
    const int E   = in_sizes[1] / 2;             // 524288
    const int h1d = in_sizes[5];                 // 256
    const int d   = in_sizes[4] / h1d;           // 128
    const int embrows = in_sizes[3] / d;         // 8193
    const int nu  = n - (embrows - 1);           // 8192
    const int ni  = n - nu;                      // 8192

    const int* srcp = ei;
    const int* dstp = ei + E;

    char* w = (char*)d_ws;
    int*   counts  = (int*)(w + 0);
    int*   row_ptr = (int*)(w + (64 << 10));
    int*   wp      = (int*)(w + (128 << 10));
    float* dinv    = (float*)(w + (192 << 10));
    unsigned short* W1t = (unsigned short*)(w + (256 << 10));
    unsigned short* W2t = (unsigned short*)(w + (320 << 10));
    unsigned short* Wlt = (unsigned short*)(w + (384 << 10));
    int2*  edges   = (int2*)(w + (1 << 20));
    unsigned short* h0b  = (unsigned short*)(w + (8  << 20));
    unsigned short* hw2b = (unsigned short*)(w + (12 << 20));
    unsigned short* h3b  = (unsigned short*)(w + (16 << 20));

    // prep: h0 bf16 + transposed bf16 weights + zero counters
    {
        int total = n * 16 + 73728 + 2 * n;
        prep_kernel<<<(total + 255) / 256, 256, 0, stream>>>(
            x, emb, W1, W2, Wl, h0b, W1t, W2t, Wlt, counts, wp, nu, n);
    }

    // graph structure (LDS-histogram based, contention-free hot paths)
    count_lds_kernel<<<256, 256, 0, stream>>>(dstp, counts, E);
    scan_kernel<<<1, 256, 0, stream>>>(counts, row_ptr, dinv, n);
    scatter_lds_kernel<<<256, 256, 0, stream>>>(srcp, dstp, row_ptr, wp, dinv, edges, E);

    // conv1 fused: agg1 -> gemm1 -> gemm2  => hw2
    fused_conv1_kernel<<<n / 16, 256, 0, stream>>>(
        h0b, hw2b, row_ptr, counts, edges, dinv, W1t, b1, W2t);

    // conv2 fused: agg2 -> gemm3  => h3
    fused_conv2_kernel<<<n / 16, 256, 0, stream>>>(
        hw2b, h3b, row_ptr, counts, edges, dinv, b2, Wlt, bl);

    // result = clip(users @ items.T, 1, 5)
    {
        dim3 g(nu / 128, ni / 128);
        final_gemm_kernel<<<g, 256, 0, stream>>>((const short*)h3b, out, nu, ni);
    }
}

// Round 11
// 203.039 us; speedup vs baseline: 1.0111x; 1.0111x over previous
//
#include <hip/hip_runtime.h>
#include <hip/hip_bf16.h>

typedef __attribute__((ext_vector_type(8))) short bf16x8;
typedef __attribute__((ext_vector_type(4))) float f32x4;

static __device__ __forceinline__ float bflo(unsigned int w) {
    union { unsigned int i; float f; } u; u.i = w << 16; return u.f;
}
static __device__ __forceinline__ float bfhi(unsigned int w) {
    union { unsigned int i; float f; } u; u.i = w & 0xffff0000u; return u.f;
}
static __device__ __forceinline__ unsigned short f2bf(float f) {
    __hip_bfloat16 h = __float2bfloat16(f);
    union { __hip_bfloat16 b; unsigned short s; } u; u.b = h; return u.s;
}

// ---------------------------------------------------------------------------
// no-op kernel: measures per-dispatch graph-replay overhead (R11 diagnostic)
// ---------------------------------------------------------------------------
__global__ void noop_kernel(int* __restrict__ p) {
    if (p) p[threadIdx.x] = 0;   // never taken (p==nullptr), keeps body non-empty
}

// ---------------------------------------------------------------------------
// degree histogram over dst
// ---------------------------------------------------------------------------
__global__ void count_kernel(const int* __restrict__ dst, int* __restrict__ counts, int E) {
    int e = blockIdx.x * blockDim.x + threadIdx.x;
    if (e < E) atomicAdd(&counts[dst[e]], 1);
}

// ---------------------------------------------------------------------------
// single-block scan, coalesced column-major bucket order.
// ---------------------------------------------------------------------------
__global__ __launch_bounds__(256) void scan_kernel(const int* __restrict__ counts,
                                                   int* __restrict__ row_ptr,
                                                   float* __restrict__ dinv, int n) {
    int t = threadIdx.x;
    int rows = n >> 8;
    int s = 0;
    for (int i = 0; i < rows; ++i) s += counts[i * 256 + t];
    __shared__ int sums[256];
    sums[t] = s;
    __syncthreads();
#pragma unroll
    for (int off = 1; off < 256; off <<= 1) {
        int v = (t >= off) ? sums[t - off] : 0;
        __syncthreads();
        sums[t] += v;
        __syncthreads();
    }
    int run = (t > 0) ? sums[t - 1] : 0;
    for (int i = 0; i < rows; ++i) {
        int v = i * 256 + t;
        int c = counts[v];
        row_ptr[v] = run;
        dinv[v] = rsqrtf((float)(c + 1));
        run += c;
    }
}

// ---------------------------------------------------------------------------
// scatter edges into CSR buckets as packed {src, dinv[src]} records
// ---------------------------------------------------------------------------
__global__ void scatter_kernel(const int* __restrict__ src, const int* __restrict__ dst,
                               const int* __restrict__ row_ptr, int* __restrict__ wp,
                               const float* __restrict__ dinv,
                               int2* __restrict__ edges, int E) {
    int e = blockIdx.x * blockDim.x + threadIdx.x;
    if (e < E) {
        int d = dst[e];
        int s = src[e];
        int p = atomicAdd(&wp[d], 1);
        int2 pk;
        pk.x = s;
        pk.y = __float_as_int(dinv[s]);
        edges[row_ptr[d] + p] = pk;
    }
}

// ---------------------------------------------------------------------------
// merged prep: h0 (bf16) + transposed bf16 weights + zero counts/wp.
// ---------------------------------------------------------------------------
__global__ void prep_kernel(const int* __restrict__ x, const float* __restrict__ emb,
                            const float* __restrict__ W1, const float* __restrict__ W2,
                            const float* __restrict__ Wl,
                            unsigned short* __restrict__ h0,
                            unsigned short* __restrict__ W1t,
                            unsigned short* __restrict__ W2t,
                            unsigned short* __restrict__ Wlt,
                            int* __restrict__ counts, int* __restrict__ wp,
                            int nu, int n) {
    int i = blockIdx.x * blockDim.x + threadIdx.x;
    int H = n * 16;
    if (i < H) {
        int node = i >> 4, c8 = i & 15;
        int row = (node < nu) ? 0 : (x[node] - nu + 1);
        float4 f0 = reinterpret_cast<const float4*>(emb)[(size_t)row * 32 + c8 * 2];
        float4 f1 = reinterpret_cast<const float4*>(emb)[(size_t)row * 32 + c8 * 2 + 1];
        union { unsigned short s[8]; uint4 v; } o;
        o.s[0] = f2bf(f0.x); o.s[1] = f2bf(f0.y); o.s[2] = f2bf(f0.z); o.s[3] = f2bf(f0.w);
        o.s[4] = f2bf(f1.x); o.s[5] = f2bf(f1.y); o.s[6] = f2bf(f1.z); o.s[7] = f2bf(f1.w);
        *reinterpret_cast<uint4*>(h0 + (size_t)node * 128 + c8 * 8) = o.v;
        return;
    }
    int j = i - H;
    if (j < 32768) {
        int nn = j >> 7, kk = j & 127;
        W1t[j] = f2bf(W1[kk * 256 + nn]);
        return;
    }
    if (j < 65536) {
        int jj = j - 32768;
        int nn = jj >> 8, kk = jj & 255;
        W2t[jj] = f2bf(W2[kk * 128 + nn]);
        return;
    }
    if (j < 73728) {
        int jj = j - 65536;
        int nn = jj >> 7, kk = jj & 127;
        Wlt[jj] = f2bf(Wl[kk * 64 + nn]);
        return;
    }
    int z = j - 73728;
    if (z < n) { counts[z] = 0; return; }
    z -= n;
    if (z < n) { wp[z] = 0; }
}

// ---------------------------------------------------------------------------
// one-wave aggregation of node v -> LDS row (bf16).
// ---------------------------------------------------------------------------
static __device__ __forceinline__ void agg_node_to_lds(
    const unsigned short* __restrict__ in, unsigned short* lds_row,
    int v, int lane, const int* __restrict__ row_ptr, const int* __restrict__ cnt,
    const int2* __restrict__ edges, const float* __restrict__ dinv,
    const float* __restrict__ bias, int relu) {
    int l16 = lane & 15;
    int g = lane >> 4;
    float acc[8] = {0.f, 0.f, 0.f, 0.f, 0.f, 0.f, 0.f, 0.f};
    int s0 = row_ptr[v];
    int s1 = s0 + cnt[v];
    int e = s0 + g;
    for (; e + 4 < s1; e += 8) {
        int2 pa = edges[e];
        int2 pb = edges[e + 4];
        float wa = __int_as_float(pa.y);
        float wb = __int_as_float(pb.y);
        uint4 ra = *reinterpret_cast<const uint4*>(in + (size_t)pa.x * 128 + l16 * 8);
        uint4 rb = *reinterpret_cast<const uint4*>(in + (size_t)pb.x * 128 + l16 * 8);
        acc[0] = fmaf(wa, bflo(ra.x), acc[0]);
        acc[1] = fmaf(wa, bfhi(ra.x), acc[1]);
        acc[2] = fmaf(wa, bflo(ra.y), acc[2]);
        acc[3] = fmaf(wa, bfhi(ra.y), acc[3]);
        acc[4] = fmaf(wa, bflo(ra.z), acc[4]);
        acc[5] = fmaf(wa, bfhi(ra.z), acc[5]);
        acc[6] = fmaf(wa, bflo(ra.w), acc[6]);
        acc[7] = fmaf(wa, bfhi(ra.w), acc[7]);
        acc[0] = fmaf(wb, bflo(rb.x), acc[0]);
        acc[1] = fmaf(wb, bfhi(rb.x), acc[1]);
        acc[2] = fmaf(wb, bflo(rb.y), acc[2]);
        acc[3] = fmaf(wb, bfhi(rb.y), acc[3]);
        acc[4] = fmaf(wb, bflo(rb.z), acc[4]);
        acc[5] = fmaf(wb, bfhi(rb.z), acc[5]);
        acc[6] = fmaf(wb, bflo(rb.w), acc[6]);
        acc[7] = fmaf(wb, bfhi(rb.w), acc[7]);
    }
    if (e < s1) {
        int2 pa = edges[e];
        float wa = __int_as_float(pa.y);
        uint4 ra = *reinterpret_cast<const uint4*>(in + (size_t)pa.x * 128 + l16 * 8);
        acc[0] = fmaf(wa, bflo(ra.x), acc[0]);
        acc[1] = fmaf(wa, bfhi(ra.x), acc[1]);
        acc[2] = fmaf(wa, bflo(ra.y), acc[2]);
        acc[3] = fmaf(wa, bfhi(ra.y), acc[3]);
        acc[4] = fmaf(wa, bflo(ra.z), acc[4]);
        acc[5] = fmaf(wa, bfhi(ra.z), acc[5]);
        acc[6] = fmaf(wa, bflo(ra.w), acc[6]);
        acc[7] = fmaf(wa, bfhi(ra.w), acc[7]);
    }
#pragma unroll
    for (int d = 0; d < 8; ++d) {
        acc[d] += __shfl_xor(acc[d], 16, 64);
        acc[d] += __shfl_xor(acc[d], 32, 64);
    }
    if (g == 0) {
        float dv = dinv[v];
        uint4 sp = *reinterpret_cast<const uint4*>(in + (size_t)v * 128 + l16 * 8);
        float self[8] = {bflo(sp.x), bfhi(sp.x), bflo(sp.y), bfhi(sp.y),
                         bflo(sp.z), bfhi(sp.z), bflo(sp.w), bfhi(sp.w)};
        union { unsigned short s[8]; uint4 u; } o;
#pragma unroll
        for (int d = 0; d < 8; ++d) {
            float val = (acc[d] + dv * self[d]) * dv;
            if (bias) val += bias[l16 * 8 + d];
            if (relu) val = fmaxf(val, 0.f);
            o.s[d] = f2bf(val);
        }
        *reinterpret_cast<uint4*>(lds_row + l16 * 8) = o.u;
    }
}

// ---------------------------------------------------------------------------
// fused conv1: block = 16 nodes. agg -> gemm1(relu) -> gemm2 -> hw2
// ---------------------------------------------------------------------------
__global__ __launch_bounds__(256) void fused_conv1_kernel(
    const unsigned short* __restrict__ h0b, unsigned short* __restrict__ hw2b,
    const int* __restrict__ row_ptr, const int* __restrict__ cnt,
    const int2* __restrict__ edges, const float* __restrict__ dinv,
    const unsigned short* __restrict__ W1t, const float* __restrict__ b1,
    const unsigned short* __restrict__ W2t) {
    __shared__ unsigned short zt[16][136];
    __shared__ unsigned short h1t[16][264];
    int wid = threadIdx.x >> 6, lane = threadIdx.x & 63;
    int base = blockIdx.x * 16;
#pragma unroll
    for (int q = 0; q < 4; ++q) {
        int loc = wid * 4 + q;
        agg_node_to_lds(h0b, &zt[loc][0], base + loc, lane, row_ptr, cnt, edges, dinv,
                        nullptr, 0);
    }
    __syncthreads();
    int lr = lane & 15, kg = (lane >> 4) * 8;
    int rq = (lane >> 4) * 4;
    {
        int bn = wid * 64;
        f32x4 acc[4] = {{0,0,0,0},{0,0,0,0},{0,0,0,0},{0,0,0,0}};
        for (int k0 = 0; k0 < 128; k0 += 32) {
            bf16x8 a = *reinterpret_cast<const bf16x8*>(&zt[lr][k0 + kg]);
#pragma unroll
            for (int c = 0; c < 4; ++c) {
                bf16x8 b = *reinterpret_cast<const bf16x8*>(W1t + (size_t)(bn + c * 16 + lr) * 128 + k0 + kg);
                acc[c] = __builtin_amdgcn_mfma_f32_16x16x32_bf16(a, b, acc[c], 0, 0, 0);
            }
        }
#pragma unroll
        for (int c = 0; c < 4; ++c) {
            int col = bn + c * 16 + lr;
            float bs = b1[col];
#pragma unroll
            for (int q = 0; q < 4; ++q) {
                float vv = fmaxf(acc[c][q] + bs, 0.f);
                h1t[rq + q][col] = f2bf(vv);
            }
        }
    }
    __syncthreads();
    {
        int bn = wid * 32;
        f32x4 acc[2] = {{0,0,0,0},{0,0,0,0}};
        for (int k0 = 0; k0 < 256; k0 += 32) {
            bf16x8 a = *reinterpret_cast<const bf16x8*>(&h1t[lr][k0 + kg]);
#pragma unroll
            for (int c = 0; c < 2; ++c) {
                bf16x8 b = *reinterpret_cast<const bf16x8*>(W2t + (size_t)(bn + c * 16 + lr) * 256 + k0 + kg);
                acc[c] = __builtin_amdgcn_mfma_f32_16x16x32_bf16(a, b, acc[c], 0, 0, 0);
            }
        }
#pragma unroll
        for (int c = 0; c < 2; ++c) {
            int col = bn + c * 16 + lr;
#pragma unroll
            for (int q = 0; q < 4; ++q)
                hw2b[(size_t)(base + rq + q) * 128 + col] = f2bf(acc[c][q]);
        }
    }
}

// ---------------------------------------------------------------------------
// fused conv2: block = 16 nodes. agg(+b2,relu) -> gemm3(+bl,relu) -> h3
// ---------------------------------------------------------------------------
__global__ __launch_bounds__(256) void fused_conv2_kernel(
    const unsigned short* __restrict__ hw2b, unsigned short* __restrict__ h3b,
    const int* __restrict__ row_ptr, const int* __restrict__ cnt,
    const int2* __restrict__ edges, const float* __restrict__ dinv,
    const float* __restrict__ b2,
    const unsigned short* __restrict__ Wlt, const float* __restrict__ bl) {
    __shared__ unsigned short ht[16][136];
    int wid = threadIdx.x >> 6, lane = threadIdx.x & 63;
    int base = blockIdx.x * 16;
#pragma unroll
    for (int q = 0; q < 4; ++q) {
        int loc = wid * 4 + q;
        agg_node_to_lds(hw2b, &ht[loc][0], base + loc, lane, row_ptr, cnt, edges, dinv,
                        b2, 1);
    }
    __syncthreads();
    int lr = lane & 15, kg = (lane >> 4) * 8;
    int rq = (lane >> 4) * 4;
    f32x4 acc = {0, 0, 0, 0};
    for (int k0 = 0; k0 < 128; k0 += 32) {
        bf16x8 a = *reinterpret_cast<const bf16x8*>(&ht[lr][k0 + kg]);
        bf16x8 b = *reinterpret_cast<const bf16x8*>(Wlt + (size_t)(wid * 16 + lr) * 128 + k0 + kg);
        acc = __builtin_amdgcn_mfma_f32_16x16x32_bf16(a, b, acc, 0, 0, 0);
    }
    int col = wid * 16 + lr;
    float bs = bl[col];
#pragma unroll
    for (int q = 0; q < 4; ++q) {
        float vv = fmaxf(acc[q] + bs, 0.f);
        h3b[(size_t)(base + rq + q) * 64 + col] = f2bf(vv);
    }
}

// ---------------------------------------------------------------------------
// final: out[i][j] = clip(dot64(users[i], items[j]), 1, 5)  via bf16 MFMA.
// ---------------------------------------------------------------------------
__global__ __launch_bounds__(256) void final_gemm_kernel(
    const short* __restrict__ h3b, float* __restrict__ out, int nu, int ni) {
    __shared__ float tile[4][16][65];
    int wid = threadIdx.x >> 6, lane = threadIdx.x & 63;
    int row0 = blockIdx.x * 128 + (wid >> 1) * 64;
    int col0 = blockIdx.y * 128 + (wid & 1) * 64;
    int lr = lane & 15;
    int kg = (lane >> 4) * 8;
    const short* Au = h3b;
    const short* Bi = h3b + (size_t)nu * 64;
    bf16x8 a[4][2], b[4][2];
#pragma unroll
    for (int r = 0; r < 4; ++r)
#pragma unroll
        for (int kt = 0; kt < 2; ++kt) {
            a[r][kt] = *reinterpret_cast<const bf16x8*>(Au + (size_t)(row0 + r * 16 + lr) * 64 + kt * 32 + kg);
            b[r][kt] = *reinterpret_cast<const bf16x8*>(Bi + (size_t)(col0 + r * 16 + lr) * 64 + kt * 32 + kg);
        }
    f32x4 acc[4][4];
#pragma unroll
    for (int r = 0; r < 4; ++r)
#pragma unroll
        for (int c = 0; c < 4; ++c) {
            f32x4 z = {0.f, 0.f, 0.f, 0.f};
            z = __builtin_amdgcn_mfma_f32_16x16x32_bf16(a[r][0], b[c][0], z, 0, 0, 0);
            z = __builtin_amdgcn_mfma_f32_16x16x32_bf16(a[r][1], b[c][1], z, 0, 0, 0);
            acc[r][c] = z;
        }
    int rq = (lane >> 4) * 4;
    int orow = lane >> 4;
#pragma unroll
    for (int r = 0; r < 4; ++r) {
        __syncthreads();
#pragma unroll
        for (int c = 0; c < 4; ++c)
#pragma unroll
            for (int q = 0; q < 4; ++q) {
                float v = acc[r][c][q];
                v = fminf(fmaxf(v, 1.f), 5.f);
                tile[wid][rq + q][c * 16 + lr] = v;
            }
        __syncthreads();
#pragma unroll
        for (int rr = 0; rr < 4; ++rr) {
            float4 vv = *reinterpret_cast<const float4*>(&tile[wid][rr * 4 + orow][lr * 4]);
            *reinterpret_cast<float4*>(
                &out[(size_t)(row0 + r * 16 + rr * 4 + orow) * ni + col0 + lr * 4]) = vv;
        }
    }
}

// ---------------------------------------------------------------------------
extern "C" void kernel_launch(void* const* d_in, const int* in_sizes, int n_in,
                              void* d_out, int out_size, void* d_ws, size_t ws_size,
                              hipStream_t stream) {
    const int*   x   = (const int*)d_in[0];
    const int*   ei  = (const int*)d_in[1];
    const float* emb = (const float*)d_in[3];
    const float* W1  = (const float*)d_in[4];
    const float* b1  = (const float*)d_in[5];
    const float* W2  = (const float*)d_in[6];
    const float* b2  = (const float*)d_in[7];
    const float* Wl  = (const float*)d_in[8];
    const float* bl  = (const float*)d_in[9];
    float* out = (float*)d_out;

    const int n   = in_sizes[0];                 // 16384
    const int E   = in_sizes[1] / 2;             // 524288
    const int h1d = in_sizes[5];                 // 256
    const int d   = in_sizes[4] / h1d;           // 128
    const int embrows = in_sizes[3] / d;         // 8193
    const int nu  = n - (embrows - 1);           // 8192
    const int ni  = n - nu;                      // 8192

    const int* srcp = ei;
    const int* dstp = ei + E;

    char* w = (char*)d_ws;
    int*   counts  = (int*)(w + 0);
    int*   row_ptr = (int*)(w + (64 << 10));
    int*   wp      = (int*)(w + (128 << 10));
    float* dinv    = (float*)(w + (192 << 10));
    unsigned short* W1t = (unsigned short*)(w + (256 << 10));
    unsigned short* W2t = (unsigned short*)(w + (320 << 10));
    unsigned short* Wlt = (unsigned short*)(w + (384 << 10));
    int2*  edges   = (int2*)(w + (1 << 20));
    unsigned short* h0b  = (unsigned short*)(w + (8  << 20));
    unsigned short* hw2b = (unsigned short*)(w + (12 << 20));
    unsigned short* h3b  = (unsigned short*)(w + (16 << 20));

    // prep: h0 bf16 + transposed bf16 weights + zero counters
    {
        int total = n * 16 + 73728 + 2 * n;
        prep_kernel<<<(total + 255) / 256, 256, 0, stream>>>(
            x, emb, W1, W2, Wl, h0b, W1t, W2t, Wlt, counts, wp, nu, n);
    }

    // graph structure
    count_kernel<<<(E + 255) / 256, 256, 0, stream>>>(dstp, counts, E);
    scan_kernel<<<1, 256, 0, stream>>>(counts, row_ptr, dinv, n);
    scatter_kernel<<<(E + 255) / 256, 256, 0, stream>>>(srcp, dstp, row_ptr, wp, dinv, edges, E);

    // conv1 fused: agg1 -> gemm1 -> gemm2  => hw2
    fused_conv1_kernel<<<n / 16, 256, 0, stream>>>(
        h0b, hw2b, row_ptr, counts, edges, dinv, W1t, b1, W2t);

    // conv2 fused: agg2 -> gemm3  => h3
    fused_conv2_kernel<<<n / 16, 256, 0, stream>>>(
        hw2b, h3b, row_ptr, counts, edges, dinv, b2, Wlt, bl);

    // result = clip(users @ items.T, 1, 5)
    {
        dim3 g(nu / 128, ni / 128);
        final_gemm_kernel<<<g, 256, 0, stream>>>((const short*)h3b, out, nu, ni);
    }

    // R11 DIAGNOSTIC: 8 no-op dispatches -> dur delta vs R9 = 8 x per-dispatch overhead
    for (int i = 0; i < 8; ++i)
        noop_kernel<<<1, 64, 0, stream>>>(nullptr);
}